// Round 2
// baseline (153.882 us; speedup 1.0000x reference)
//
#include <hip/hip_runtime.h>

// TV loss via exact spatial-domain identity of the FFT pipeline:
//   gx[y,x] = in[y,x] - in[y,(x+1)%W]
//   gy[y,x] = in[y,x] - in[(y+1)%H,x]
//   result  = sum(sqrt(gx^2 + gy^2)) / (B*C*H*W)
// Shapes fixed by setup_inputs(): B=32, C=3, H=512, W=512 (fp32).
//
// Layout: each thread owns (plane p, row-chunk, x4) and walks 16 consecutive
// rows, reusing the down-neighbor row register as next iteration's center
// (each row fetched once; 17/16 total overfetch). x-wrap neighbor comes from
// __shfl_down; only lane 63 per wave does a 4B cached load.

#define DIM_H 512
#define DIM_W 512
#define PLANES 96                       // B*C
#define TOTAL (PLANES * DIM_H * DIM_W)  // 25165824 elements
#define W4 128                          // float4 per row
#define CHUNK 16                        // rows per thread
#define CHUNKS (DIM_H / CHUNK)          // 32
#define NTHREADS 256
#define NBLOCKS (PLANES * CHUNKS * W4 / NTHREADS)  // 1536

__global__ __launch_bounds__(NTHREADS) void tv_partial(const float* __restrict__ in,
                                                       float* __restrict__ partial) {
    const float4* __restrict__ in4 = (const float4*)in;
    int t = blockIdx.x * NTHREADS + threadIdx.x;
    int x4    = t & (W4 - 1);
    int chunk = (t >> 7) & (CHUNKS - 1);
    int p     = t >> 12;                 // / (W4*CHUNKS)

    int lane = threadIdx.x & 63;
    int base = (p << 16) + (chunk << 11) + x4;  // float4 index of first row
    int wrap0 = (p << 16) + x4;                 // row 0 of this plane (y-wrap)
    int srow = (p << 18) + (((x4 << 2) + 4) & (DIM_W - 1));  // scalar wrap base

    float s = 0.0f;
    int idx = base;
    float4 c = in4[idx];

    #pragma unroll
    for (int j = 0; j < CHUNK; ++j) {
        int nidx = idx + W4;
        if (chunk == CHUNKS - 1 && j == CHUNK - 1) nidx = wrap0;  // y-wrap to row 0
        float4 d = in4[nidx];

        // right neighbor of c.w: next lane's c.x (lanes 0..62)
        float ex = __shfl_down(c.x, 1, 64);
        if (lane == 63) {
            int y = (chunk << 4) + j;
            ex = in[srow + (y << 9)];
        }

        float dx0 = c.x - c.y, dy0 = c.x - d.x;
        float dx1 = c.y - c.z, dy1 = c.y - d.y;
        float dx2 = c.z - c.w, dy2 = c.z - d.z;
        float dx3 = c.w - ex,  dy3 = c.w - d.w;

        s += sqrtf(dx0 * dx0 + dy0 * dy0);
        s += sqrtf(dx1 * dx1 + dy1 * dy1);
        s += sqrtf(dx2 * dx2 + dy2 * dy2);
        s += sqrtf(dx3 * dx3 + dy3 * dy3);

        c = d;
        idx += W4;
    }

    // wave (64-lane) reduction
    #pragma unroll
    for (int off = 32; off > 0; off >>= 1)
        s += __shfl_down(s, off, 64);

    __shared__ float smem[NTHREADS / 64];
    int wave = threadIdx.x >> 6;
    if (lane == 0) smem[wave] = s;
    __syncthreads();
    if (threadIdx.x == 0)
        partial[blockIdx.x] = smem[0] + smem[1] + smem[2] + smem[3];
}

__global__ __launch_bounds__(256) void tv_final(const float* __restrict__ partial,
                                                float* __restrict__ out) {
    float s = 0.0f;
    for (int i = threadIdx.x; i < NBLOCKS; i += 256)
        s += partial[i];

    #pragma unroll
    for (int off = 32; off > 0; off >>= 1)
        s += __shfl_down(s, off, 64);

    __shared__ float smem[4];
    int lane = threadIdx.x & 63;
    int wave = threadIdx.x >> 6;
    if (lane == 0) smem[wave] = s;
    __syncthreads();
    if (threadIdx.x == 0)
        out[0] = (smem[0] + smem[1] + smem[2] + smem[3]) * (1.0f / (float)TOTAL);
}

extern "C" void kernel_launch(void* const* d_in, const int* in_sizes, int n_in,
                              void* d_out, int out_size, void* d_ws, size_t ws_size,
                              hipStream_t stream) {
    const float* in = (const float*)d_in[0];
    float* out = (float*)d_out;
    float* partial = (float*)d_ws;  // NBLOCKS floats of scratch

    tv_partial<<<NBLOCKS, NTHREADS, 0, stream>>>(in, partial);
    tv_final<<<1, 256, 0, stream>>>(partial, out);
}

// Round 3
// 147.351 us; speedup vs baseline: 1.0443x; 1.0443x over previous
//
#include <hip/hip_runtime.h>

// TV loss via exact spatial-domain identity of the FFT pipeline:
//   gx[y,x] = in[y,x] - in[y,(x+1)%W]
//   gy[y,x] = in[y,x] - in[(y+1)%H,x]
//   result  = sum(sqrt(gx^2 + gy^2)) / (B*C*H*W)
// Shapes fixed by setup_inputs(): B=32, C=3, H=512, W=512 (fp32).
//
// Layout: one wave owns a full 512-float row (8 floats/lane = 2 float4 loads),
// and walks an 8-row strip, reusing the down-neighbor row registers as next
// iteration's center (9 rows fetched per 8 computed, 12.5% overlap).
// All x-neighbors are in-register: c0.w->c1.x intra-thread; c1.w -> next
// lane's c0.x via one __shfl with (lane+1)&63, which also handles the x-wrap
// (lane 63 -> lane 0). No divergence, no scalar loads in the loop.

#define DIM_H 512
#define DIM_W 512
#define PLANES 96                       // B*C
#define TOTAL (PLANES * DIM_H * DIM_W)  // 25165824 elements
#define W4 128                          // float4 per row
#define CHUNK 8                         // rows per wave-strip
#define CHUNKS (DIM_H / CHUNK)          // 64
#define NTHREADS 256
#define NBLOCKS (PLANES * CHUNKS / 4)   // 1536 (4 waves per block)

__global__ __launch_bounds__(NTHREADS) void tv_partial(const float* __restrict__ in,
                                                       float* __restrict__ partial) {
    const float4* __restrict__ in4 = (const float4*)in;
    int wid  = blockIdx.x * (NTHREADS / 64) + (threadIdx.x >> 6);
    int lane = threadIdx.x & 63;
    int p     = wid >> 6;       // / CHUNKS
    int chunk = wid & (CHUNKS - 1);

    // float4 indices: plane stride 1<<16, row stride 128, lane covers 2 f4
    int idx  = (p << 16) + (chunk << 10) + (lane << 1);  // chunk*CHUNK rows = chunk<<10
    int wrap = (p << 16) + (lane << 1);                  // row 0 of this plane
    int src  = (lane + 1) & 63;                          // right-neighbor lane (wraps)

    float4 c0 = in4[idx];
    float4 c1 = in4[idx + 1];
    float s = 0.0f;

    #pragma unroll
    for (int j = 0; j < CHUNK; ++j) {
        int nidx = idx + W4;
        if (chunk == CHUNKS - 1 && j == CHUNK - 1) nidx = wrap;  // y-wrap
        float4 d0 = in4[nidx];
        float4 d1 = in4[nidx + 1];

        float e = __shfl(c0.x, src, 64);  // right neighbor of c1.w (handles x-wrap)

        float dx0 = c0.x - c0.y, dy0 = c0.x - d0.x;
        float dx1 = c0.y - c0.z, dy1 = c0.y - d0.y;
        float dx2 = c0.z - c0.w, dy2 = c0.z - d0.z;
        float dx3 = c0.w - c1.x, dy3 = c0.w - d0.w;
        float dx4 = c1.x - c1.y, dy4 = c1.x - d1.x;
        float dx5 = c1.y - c1.z, dy5 = c1.y - d1.y;
        float dx6 = c1.z - c1.w, dy6 = c1.z - d1.z;
        float dx7 = c1.w - e,    dy7 = c1.w - d1.w;

        s += sqrtf(dx0 * dx0 + dy0 * dy0);
        s += sqrtf(dx1 * dx1 + dy1 * dy1);
        s += sqrtf(dx2 * dx2 + dy2 * dy2);
        s += sqrtf(dx3 * dx3 + dy3 * dy3);
        s += sqrtf(dx4 * dx4 + dy4 * dy4);
        s += sqrtf(dx5 * dx5 + dy5 * dy5);
        s += sqrtf(dx6 * dx6 + dy6 * dy6);
        s += sqrtf(dx7 * dx7 + dy7 * dy7);

        c0 = d0;
        c1 = d1;
        idx = nidx;
    }

    // wave (64-lane) reduction
    #pragma unroll
    for (int off = 32; off > 0; off >>= 1)
        s += __shfl_down(s, off, 64);

    __shared__ float smem[NTHREADS / 64];
    int wave = threadIdx.x >> 6;
    if (lane == 0) smem[wave] = s;
    __syncthreads();
    if (threadIdx.x == 0)
        partial[blockIdx.x] = smem[0] + smem[1] + smem[2] + smem[3];
}

__global__ __launch_bounds__(256) void tv_final(const float* __restrict__ partial,
                                                float* __restrict__ out) {
    float s = 0.0f;
    for (int i = threadIdx.x; i < NBLOCKS; i += 256)
        s += partial[i];

    #pragma unroll
    for (int off = 32; off > 0; off >>= 1)
        s += __shfl_down(s, off, 64);

    __shared__ float smem[4];
    int lane = threadIdx.x & 63;
    int wave = threadIdx.x >> 6;
    if (lane == 0) smem[wave] = s;
    __syncthreads();
    if (threadIdx.x == 0)
        out[0] = (smem[0] + smem[1] + smem[2] + smem[3]) * (1.0f / (float)TOTAL);
}

extern "C" void kernel_launch(void* const* d_in, const int* in_sizes, int n_in,
                              void* d_out, int out_size, void* d_ws, size_t ws_size,
                              hipStream_t stream) {
    const float* in = (const float*)d_in[0];
    float* out = (float*)d_out;
    float* partial = (float*)d_ws;  // NBLOCKS floats of scratch

    tv_partial<<<NBLOCKS, NTHREADS, 0, stream>>>(in, partial);
    tv_final<<<1, 256, 0, stream>>>(partial, out);
}

// Round 4
// 145.806 us; speedup vs baseline: 1.0554x; 1.0106x over previous
//
#include <hip/hip_runtime.h>

// TV loss via exact spatial-domain identity of the FFT pipeline:
//   gx[y,x] = in[y,x] - in[y,(x+1)%W]
//   gy[y,x] = in[y,x] - in[(y+1)%H,x]
//   result  = sum(sqrt(gx^2 + gy^2)) / (B*C*H*W)
// Shapes fixed: B=32, C=3, H=512, W=512 (fp32).
//
// One wave owns a full 512-float row: lane l loads f4[l] (floats 4l..4l+3)
// and f4[l+64] (floats 256+4l..). Both loads are fully-coalesced contiguous
// 1-KB wave transactions. Each thread covers a 4-row strip: 10 independent
// loads (5 rows x 2) issued upfront -> max MLP, no register-carry chain.
// Right-neighbors via two __shfl((lane+1)&63) + lane-63 swap (handles both
// the half-row seam at float 256 and the x-wrap at float 511->0).

#define DIM_H 512
#define DIM_W 512
#define PLANES 96                        // B*C
#define TOTAL (PLANES * DIM_H * DIM_W)   // 25165824
#define W4 128                           // float4 per row
#define STRIPS_PER_PLANE 128             // 512 rows / 4-row strips
#define NTHREADS 256
#define NBLOCKS (PLANES * STRIPS_PER_PLANE / 4)  // 3072 (4 waves/block)

__global__ __launch_bounds__(NTHREADS) void tv_partial(const float* __restrict__ in,
                                                       float* __restrict__ partial) {
    const float4* __restrict__ in4 = (const float4*)in;
    int wid  = blockIdx.x * (NTHREADS / 64) + (threadIdx.x >> 6);
    int lane = threadIdx.x & 63;
    int p = wid >> 7;                    // plane
    int k = wid & (STRIPS_PER_PLANE - 1);

    int rb  = (p << 16) + (k << 9) + lane;              // f4 idx, strip row 0
    int rb4 = (k == STRIPS_PER_PLANE - 1) ? ((p << 16) + lane)   // y-wrap
                                          : (rb + 4 * W4);

    // 10 independent fully-coalesced loads, issued before any compute.
    float4 a0 = in4[rb];            float4 b0 = in4[rb + 64];
    float4 a1 = in4[rb + 128];      float4 b1 = in4[rb + 192];
    float4 a2 = in4[rb + 256];      float4 b2 = in4[rb + 320];
    float4 a3 = in4[rb + 384];      float4 b3 = in4[rb + 448];
    float4 a4 = in4[rb4];           float4 b4 = in4[rb4 + 64];

    int src = (lane + 1) & 63;
    bool last = (lane == 63);
    float s = 0.0f;

#define TV_ROW(A, B, DA, DB)                                                   \
    do {                                                                       \
        float n0 = __shfl((A).x, src, 64);                                     \
        float n1 = __shfl((B).x, src, 64);                                     \
        float e0 = last ? n1 : n0; /* right of A.w (float 4l+3) */             \
        float e1 = last ? n0 : n1; /* right of B.w (handles x-wrap) */         \
        float t;                                                               \
        t = (A).x - (A).y; s += sqrtf(t*t + ((A).x-(DA).x)*((A).x-(DA).x));    \
        t = (A).y - (A).z; s += sqrtf(t*t + ((A).y-(DA).y)*((A).y-(DA).y));    \
        t = (A).z - (A).w; s += sqrtf(t*t + ((A).z-(DA).z)*((A).z-(DA).z));    \
        t = (A).w - e0;    s += sqrtf(t*t + ((A).w-(DA).w)*((A).w-(DA).w));    \
        t = (B).x - (B).y; s += sqrtf(t*t + ((B).x-(DB).x)*((B).x-(DB).x));    \
        t = (B).y - (B).z; s += sqrtf(t*t + ((B).y-(DB).y)*((B).y-(DB).y));    \
        t = (B).z - (B).w; s += sqrtf(t*t + ((B).z-(DB).z)*((B).z-(DB).z));    \
        t = (B).w - e1;    s += sqrtf(t*t + ((B).w-(DB).w)*((B).w-(DB).w));    \
    } while (0)

    TV_ROW(a0, b0, a1, b1);
    TV_ROW(a1, b1, a2, b2);
    TV_ROW(a2, b2, a3, b3);
    TV_ROW(a3, b3, a4, b4);
#undef TV_ROW

    // wave reduction
    #pragma unroll
    for (int off = 32; off > 0; off >>= 1)
        s += __shfl_down(s, off, 64);

    __shared__ float smem[NTHREADS / 64];
    int wave = threadIdx.x >> 6;
    if (lane == 0) smem[wave] = s;
    __syncthreads();
    if (threadIdx.x == 0)
        partial[blockIdx.x] = smem[0] + smem[1] + smem[2] + smem[3];
}

__global__ __launch_bounds__(256) void tv_final(const float* __restrict__ partial,
                                                float* __restrict__ out) {
    float s = 0.0f;
    for (int i = threadIdx.x; i < NBLOCKS; i += 256)
        s += partial[i];

    #pragma unroll
    for (int off = 32; off > 0; off >>= 1)
        s += __shfl_down(s, off, 64);

    __shared__ float smem[4];
    int lane = threadIdx.x & 63;
    int wave = threadIdx.x >> 6;
    if (lane == 0) smem[wave] = s;
    __syncthreads();
    if (threadIdx.x == 0)
        out[0] = (smem[0] + smem[1] + smem[2] + smem[3]) * (1.0f / (float)TOTAL);
}

extern "C" void kernel_launch(void* const* d_in, const int* in_sizes, int n_in,
                              void* d_out, int out_size, void* d_ws, size_t ws_size,
                              hipStream_t stream) {
    const float* in = (const float*)d_in[0];
    float* out = (float*)d_out;
    float* partial = (float*)d_ws;  // NBLOCKS floats of scratch

    tv_partial<<<NBLOCKS, NTHREADS, 0, stream>>>(in, partial);
    tv_final<<<1, 256, 0, stream>>>(partial, out);
}

// Round 6
// 140.649 us; speedup vs baseline: 1.0941x; 1.0367x over previous
//
#include <hip/hip_runtime.h>

// TV loss via exact spatial-domain identity of the FFT pipeline:
//   gx[y,x] = in[y,x] - in[y,(x+1)%W]
//   gy[y,x] = in[y,x] - in[(y+1)%H,x]
//   result  = sum(sqrt(gx^2 + gy^2)) / (B*C*H*W)
// Shapes fixed: B=32, C=3, H=512, W=512 (fp32).
//
// One wave owns full 512-float rows (lane l holds floats 4l..4l+3 and
// 256+4l..256+4l+3, two coalesced 1-KB dwordx4 loads per row). Each wave
// walks a 4-row strip with an explicit 2-row-ahead double buffer: only
// 3 row-pairs (24 VGPRs payload) live at once -> __launch_bounds__(256,8)
// keeps VGPR<=64 for 8 waves/SIMD. All loads nontemporal (read-once
// streaming, evict-first) to avoid L2/L3 replacement thrash.
// Right-neighbors via two __shfl((lane+1)&63) + lane-63 swap (handles the
// half-row seam at float 256 and the x-wrap 511->0).

#define DIM_H 512
#define DIM_W 512
#define PLANES 96                        // B*C
#define TOTAL (PLANES * DIM_H * DIM_W)   // 25165824
#define W4 128                           // float4 per row
#define STRIPS_PER_PLANE 128             // 512 rows / 4
#define NTHREADS 256
#define NBLOCKS (PLANES * STRIPS_PER_PLANE / 4)  // 3072 (4 waves/block)

// native clang vector type — __builtin_nontemporal_load requires this
typedef float vf4 __attribute__((ext_vector_type(4)));

struct F4 { float x, y, z, w; };

__device__ __forceinline__ F4 ldnt(const float* p) {
    vf4 v = __builtin_nontemporal_load((const vf4*)p);
    F4 r;
    r.x = v[0]; r.y = v[1]; r.z = v[2]; r.w = v[3];
    return r;
}

__global__ __launch_bounds__(NTHREADS, 8) void tv_partial(const float* __restrict__ in,
                                                          float* __restrict__ partial) {
    int wid  = blockIdx.x * (NTHREADS / 64) + (threadIdx.x >> 6);
    int lane = threadIdx.x & 63;
    int p = wid >> 7;                    // plane
    int k = wid & (STRIPS_PER_PLANE - 1);

    int rb = (p << 16) + (k << 9) + lane;               // f4 idx of strip row 0
    int r4 = (k == STRIPS_PER_PLANE - 1) ? ((p << 16) + lane)  // y-wrap row
                                         : (rb + 4 * W4);

    int src = (lane + 1) & 63;
    bool last = (lane == 63);
    float s = 0.0f;

#define TV_ROW(A, B, DA, DB)                                                   \
    do {                                                                       \
        float n0 = __shfl((A).x, src, 64);                                     \
        float n1 = __shfl((B).x, src, 64);                                     \
        float e0 = last ? n1 : n0; /* right of A.w */                          \
        float e1 = last ? n0 : n1; /* right of B.w (x-wrap) */                 \
        float t;                                                               \
        t = (A).x - (A).y; s += sqrtf(t*t + ((A).x-(DA).x)*((A).x-(DA).x));    \
        t = (A).y - (A).z; s += sqrtf(t*t + ((A).y-(DA).y)*((A).y-(DA).y));    \
        t = (A).z - (A).w; s += sqrtf(t*t + ((A).z-(DA).z)*((A).z-(DA).z));    \
        t = (A).w - e0;    s += sqrtf(t*t + ((A).w-(DA).w)*((A).w-(DA).w));    \
        t = (B).x - (B).y; s += sqrtf(t*t + ((B).x-(DB).x)*((B).x-(DB).x));    \
        t = (B).y - (B).z; s += sqrtf(t*t + ((B).y-(DB).y)*((B).y-(DB).y));    \
        t = (B).z - (B).w; s += sqrtf(t*t + ((B).z-(DB).z)*((B).z-(DB).z));    \
        t = (B).w - e1;    s += sqrtf(t*t + ((B).w-(DB).w)*((B).w-(DB).w));    \
    } while (0)

    // Double-buffered pipeline: 3 row-pairs live (A0/B0, A1/B1, A2/B2).
    F4 A0 = ldnt(in + 4 * (rb));           F4 B0 = ldnt(in + 4 * (rb + 64));
    F4 A1 = ldnt(in + 4 * (rb + 128));     F4 B1 = ldnt(in + 4 * (rb + 192));

    F4 A2 = ldnt(in + 4 * (rb + 256));     F4 B2 = ldnt(in + 4 * (rb + 320));
    TV_ROW(A0, B0, A1, B1);                // row 0 vs row 1

    A0 = ldnt(in + 4 * (rb + 384));        B0 = ldnt(in + 4 * (rb + 448));
    TV_ROW(A1, B1, A2, B2);                // row 1 vs row 2

    A1 = ldnt(in + 4 * (r4));              B1 = ldnt(in + 4 * (r4 + 64));
    TV_ROW(A2, B2, A0, B0);                // row 2 vs row 3

    TV_ROW(A0, B0, A1, B1);                // row 3 vs row 4 (wrap)
#undef TV_ROW

    // wave reduction
    #pragma unroll
    for (int off = 32; off > 0; off >>= 1)
        s += __shfl_down(s, off, 64);

    __shared__ float smem[NTHREADS / 64];
    int wave = threadIdx.x >> 6;
    if (lane == 0) smem[wave] = s;
    __syncthreads();
    if (threadIdx.x == 0)
        partial[blockIdx.x] = smem[0] + smem[1] + smem[2] + smem[3];
}

__global__ __launch_bounds__(256) void tv_final(const float* __restrict__ partial,
                                                float* __restrict__ out) {
    float s = 0.0f;
    for (int i = threadIdx.x; i < NBLOCKS; i += 256)
        s += partial[i];

    #pragma unroll
    for (int off = 32; off > 0; off >>= 1)
        s += __shfl_down(s, off, 64);

    __shared__ float smem[4];
    int lane = threadIdx.x & 63;
    int wave = threadIdx.x >> 6;
    if (lane == 0) smem[wave] = s;
    __syncthreads();
    if (threadIdx.x == 0)
        out[0] = (smem[0] + smem[1] + smem[2] + smem[3]) * (1.0f / (float)TOTAL);
}

extern "C" void kernel_launch(void* const* d_in, const int* in_sizes, int n_in,
                              void* d_out, int out_size, void* d_ws, size_t ws_size,
                              hipStream_t stream) {
    const float* in = (const float*)d_in[0];
    float* out = (float*)d_out;
    float* partial = (float*)d_ws;  // NBLOCKS floats of scratch

    tv_partial<<<NBLOCKS, NTHREADS, 0, stream>>>(in, partial);
    tv_final<<<1, 256, 0, stream>>>(partial, out);
}